// Round 13
// baseline (1455.550 us; speedup 1.0000x reference)
//
#include <hip/hip_runtime.h>

// QRNN: B=8 T=2048 C=512 U=512 W=2
// R10 — single-dispatch scan via decoupled lookback (rocPRIM-style).
// R9 post-mortem: grid.sync() cost ~100us each on gfx950 (scan_fused 231us,
// VALUBusy 1.6% = 98% stalled). Boundary-reduction idea retained, barrier
// replaced with distributed per-chunk flag protocol (waits only on lower
// block IDs; all 1024 blocks co-resident via launch_bounds(256,4)).
// Graph: prep (+flag zeroing) -> gemm (byte-identical) -> scan_one. 3 dispatches.

#define Bn 8
#define Tn 2048
#define Cn 512
#define Un 512
#define Nn 1536
#define Kn 1024
#define Mn (Bn * Tn)
#define NC 128  // chunks per sequence
#define CL 16   // chunk length (NC*CL == Tn)
#define CONVX_BLOCKS ((Bn * (Tn + 1) * Cn / 8) / 256)  // 4098
#define CONVK_BLOCKS (32 * 48)                         // 1536
#define FLAG_BLOCKS 4                                  // zero 1024 flags

using bf16x8 = __attribute__((ext_vector_type(8))) __bf16;
using f32x4  = __attribute__((ext_vector_type(4))) float;
using ushort8v = __attribute__((ext_vector_type(8))) unsigned short;

__device__ __forceinline__ void async16(const void* g, void* l) {
  __builtin_amdgcn_global_load_lds((const __attribute__((address_space(1))) void*)g,
                                   (__attribute__((address_space(3))) void*)l, 16, 0, 0);
}

__device__ __forceinline__ unsigned short f2bf(float v) {
  union { float f; unsigned u; } c; c.f = v;
  unsigned u = c.u;
  return (unsigned short)((u + 0x7fffu + ((u >> 16) & 1u)) >> 16);  // RNE
}

__device__ __forceinline__ float bf2f(unsigned short h) {
  union { unsigned u; float f; } c; c.u = ((unsigned)h) << 16;
  return c.f;
}

__device__ __forceinline__ float fast_sigmoid(float x) {
  float e = __builtin_amdgcn_exp2f(-1.4426950408889634f * x);
  return __builtin_amdgcn_rcpf(1.0f + e);
}
__device__ __forceinline__ float fast_tanh(float x) {
  float e = __builtin_amdgcn_exp2f(-2.8853900817779268f * x);
  return 2.0f * __builtin_amdgcn_rcpf(1.0f + e) - 1.0f;
}

// ---- 1. prep: conv_x + conv_k + flag zeroing (block-range split) ------------
__global__ __launch_bounds__(256) void prep(const float* __restrict__ x,
                                            unsigned short* __restrict__ xb,
                                            const float* __restrict__ kern,
                                            unsigned short* __restrict__ kT,
                                            int* __restrict__ flags) {
  __shared__ float tile[32][33];
  if ((int)blockIdx.x < CONVX_BLOCKS) {
    // conv_x: x -> padded bf16, 8 elems/thread
    int idx = blockIdx.x * 256 + threadIdx.x;   // over B*(T+1)*C/8
    int c8  = idx & 63;                         // C/8 = 64
    int row = idx >> 6;                         // b*(T+1)+t
    int b   = row / (Tn + 1);
    int t   = row - b * (Tn + 1);
    ushort8v ov;
    if (t == 0) {
#pragma unroll
      for (int i = 0; i < 8; i++) ov[i] = 0;
    } else {
      const float* xp = x + (size_t)(b * Tn + t - 1) * Cn + c8 * 8;
      float4 v0 = *(const float4*)xp;
      float4 v1 = *(const float4*)(xp + 4);
      ov[0] = f2bf(v0.x); ov[1] = f2bf(v0.y); ov[2] = f2bf(v0.z); ov[3] = f2bf(v0.w);
      ov[4] = f2bf(v1.x); ov[5] = f2bf(v1.y); ov[6] = f2bf(v1.z); ov[7] = f2bf(v1.w);
    }
    *(ushort8v*)(xb + (size_t)row * Cn + c8 * 8) = ov;
  } else if ((int)blockIdx.x < CONVX_BLOCKS + CONVK_BLOCKS) {
    // conv_k: kernel -> bf16 transposed [N][K]
    int bid = blockIdx.x - CONVX_BLOCKS;
    int kb = bid & 31, nb = bid >> 5;           // 32 x 48
    int tx = threadIdx.x & 31, ty = threadIdx.x >> 5;
#pragma unroll
    for (int i = 0; i < 4; i++)
      tile[ty + i * 8][tx] = kern[(size_t)(kb * 32 + ty + i * 8) * Nn + nb * 32 + tx];
    __syncthreads();
#pragma unroll
    for (int i = 0; i < 4; i++) {
      int n = nb * 32 + ty + i * 8;
      int k = kb * 32 + tx;
      kT[(size_t)n * Kn + k] = f2bf(tile[tx][ty + i * 8]);
    }
  } else {
    // zero the 1024 lookback flags (stream-ordered before scan_one)
    int bid = blockIdx.x - CONVX_BLOCKS - CONVK_BLOCKS;   // [0,4)
    flags[bid * 256 + threadIdx.x] = 0;
  }
}

// ---- 2. MFMA GEMM + activation epilogue (unchanged from R5) -----------------
__global__ __launch_bounds__(256) void gemm_gates(const unsigned short* __restrict__ xb,
                                                  const unsigned short* __restrict__ kT,
                                                  const float* __restrict__ bias,
                                                  unsigned short* __restrict__ gates) {
  __shared__ unsigned short As[128 * 64];   // 16 KB
  __shared__ unsigned short Bs[128 * 64];   // 16 KB
  const int tid = threadIdx.x;
  const int m0 = blockIdx.x * 128;
  const int n0 = blockIdx.y * 128;
  const int batch = m0 / Tn;                // tiles never cross batch
  const int lane = tid & 63;
  const int w = tid >> 6, wr = w >> 1, wc = w & 1;

  const int srow = (w << 3) + (lane >> 3);        // + j*32 per call
  const int skq  = (lane & 7) ^ (lane >> 3);      // frag index this lane fetches
  const unsigned short* aStage = xb + (size_t)(m0 + batch + srow) * Cn + (skq << 3);
  const unsigned short* bStage = kT + (size_t)(n0 + srow) * Kn + (skq << 3);

  f32x4 zero = {0.f, 0.f, 0.f, 0.f};
  f32x4 acc[4][4];
#pragma unroll
  for (int i = 0; i < 4; i++)
#pragma unroll
    for (int j = 0; j < 4; j++) acc[i][j] = zero;

  const int rA0 = wr * 64 + (lane & 15);    // frag row base for A reads
  const int rB0 = wc * 64 + (lane & 15);
  const int swz = lane & 7;                 // row&7 for frag reads

  for (int k0 = 0; k0 < Kn; k0 += 64) {
#pragma unroll
    for (int j = 0; j < 4; j++) {
      async16(aStage + (size_t)(j << 5) * Cn + k0, &As[(j * 256 + tid) * 8]);
      async16(bStage + (size_t)(j << 5) * Kn + k0, &Bs[(j * 256 + tid) * 8]);
    }
    __builtin_amdgcn_s_waitcnt(0);
    __syncthreads();

#pragma unroll
    for (int ks = 0; ks < 2; ks++) {
      const int col = (((ks << 2) + (lane >> 4)) ^ swz) << 3;  // swizzled 16B col
      bf16x8 af[4], bf[4];
#pragma unroll
      for (int i = 0; i < 4; i++) {
        af[i] = *(const bf16x8*)&As[(rA0 + i * 16) * 64 + col];
        bf[i] = *(const bf16x8*)&Bs[(rB0 + i * 16) * 64 + col];
      }
#pragma unroll
      for (int i = 0; i < 4; i++)
#pragma unroll
        for (int j = 0; j < 4; j++)
          acc[i][j] = __builtin_amdgcn_mfma_f32_16x16x32_bf16(af[i], bf[j], acc[i][j], 0, 0, 0);
    }
    __syncthreads();
  }

  const int region = blockIdx.y >> 2;       // 0=z(tanh) 1=f(sig) 2=o(sig)
  const int rowB = wr * 64 + (lane >> 4) * 4;
  const int colB = wc * 64 + (lane & 15);
#pragma unroll
  for (int i = 0; i < 4; i++)
#pragma unroll
    for (int j = 0; j < 4; j++)
#pragma unroll
      for (int r = 0; r < 4; r++) {
        int mm = m0 + rowB + i * 16 + r;
        int nn = n0 + colB + j * 16;
        float g = acc[i][j][r] + bias[nn];
        float a = (region == 0) ? fast_tanh(g) : fast_sigmoid(g);
        gates[(size_t)mm * Nn + nn] = f2bf(a);
      }
}

// ---- 3. single-dispatch scan with decoupled lookback ------------------------
// 1024 blocks (= B*NC chunks) x 256 thr; u = tid and tid+256.
// flag[chunk]: 0=none, 1=aggregate published, 2=inclusive prefix published.
// Deadlock-safe: waits only on lower chunk ids; launch_bounds(256,4) caps
// VGPR at 128 -> 4 blocks/CU -> all 1024 blocks co-resident.
__global__ __launch_bounds__(256, 4) void scan_one(
    const unsigned short* __restrict__ gates,
    float* __restrict__ aggA, float* __restrict__ aggB,
    float* __restrict__ prefH,
    const float* __restrict__ init,
    float* __restrict__ out,
    int* __restrict__ flags) {
  __shared__ int lds_flag;
  const int tid = threadIdx.x;
  const int chunk = blockIdx.x;             // b*NC + c
  const int b = chunk >> 7, c = chunk & (NC - 1);
  const int u0 = tid, u1 = tid + 256;
  const int batch_lo = chunk & ~(NC - 1);   // b*NC
  const unsigned short* gp = gates + (size_t)(b * Tn + c * CL) * Nn;

  // ---- pass 1: local affine aggregate over CL steps (h_end = a*h_start + bv)
  float a0 = 1.f, bv0 = 0.f, a1 = 1.f, bv1 = 0.f;
  {
    const unsigned short* g1 = gp;
#pragma unroll
    for (int t = 0; t < CL; t++) {
      float z0 = bf2f(g1[u0]), f0 = bf2f(g1[Un + u0]);
      float z1 = bf2f(g1[u1]), f1 = bf2f(g1[Un + u1]);
      a0 *= f0; bv0 = f0 * bv0 + (1.f - f0) * z0;
      a1 *= f1; bv1 = f1 * bv1 + (1.f - f1) * z1;
      g1 += Nn;
    }
  }
  const size_t base = (size_t)chunk * Un;
  aggA[base + u0] = a0; aggB[base + u0] = bv0;
  aggA[base + u1] = a1; aggB[base + u1] = bv1;
  __syncthreads();
  __threadfence();
  if (tid == 0) atomicExch(&flags[chunk], 1);

  // ---- lookback: compute h_start
  float h0, h1;
  if (c == 0) {
    h0 = init[u0]; h1 = init[u1];
  } else {
    float cA0 = 1.f, cB0 = 0.f, cA1 = 1.f, cB1 = 0.f;  // h_start = cA*X + cB
    int cp = chunk - 1;
    for (;;) {
      int f;
      for (;;) {
        if (tid == 0) lds_flag = atomicAdd(&flags[cp], 0);
        __syncthreads();
        f = lds_flag;
        __syncthreads();
        if (f) break;
      }
      __threadfence();
      const size_t pb = (size_t)cp * Un;
      if (f == 2) {                          // inclusive prefix known: done
        float p0 = prefH[pb + u0], p1 = prefH[pb + u1];
        h0 = cA0 * p0 + cB0;
        h1 = cA1 * p1 + cB1;
        break;
      }
      // compose this chunk's aggregate: cur = cur o agg
      float gA0 = aggA[pb + u0], gB0 = aggB[pb + u0];
      float gA1 = aggA[pb + u1], gB1 = aggB[pb + u1];
      cB0 = cA0 * gB0 + cB0;  cA0 *= gA0;
      cB1 = cA1 * gB1 + cB1;  cA1 *= gA1;
      cp--;
      if (cp < batch_lo) {                   // reached batch start: apply init
        h0 = cA0 * init[u0] + cB0;
        h1 = cA1 * init[u1] + cB1;
        break;
      }
    }
  }

  // ---- publish inclusive prefix (h at end of this chunk)
  prefH[base + u0] = a0 * h0 + bv0;
  prefH[base + u1] = a1 * h1 + bv1;
  __syncthreads();
  __threadfence();
  if (tid == 0) atomicExch(&flags[chunk], 2);

  // ---- pass 2: replay chunk from h_start, apply output gate, store
  float* op = out + (size_t)(b * Tn + c * CL) * Un;
#pragma unroll
  for (int t = 0; t < CL; t++) {
    float z0 = bf2f(gp[u0]), f0 = bf2f(gp[Un + u0]), o0 = bf2f(gp[2 * Un + u0]);
    float z1 = bf2f(gp[u1]), f1 = bf2f(gp[Un + u1]), o1 = bf2f(gp[2 * Un + u1]);
    h0 = f0 * h0 + (1.f - f0) * z0;
    h1 = f1 * h1 + (1.f - f1) * z1;
    op[u0] = h0 * o0;
    op[u1] = h1 * o1;
    gp += Nn;
    op += Un;
  }
}

extern "C" void kernel_launch(void* const* d_in, const int* in_sizes, int n_in,
                              void* d_out, int out_size, void* d_ws, size_t ws_size,
                              hipStream_t stream) {
  const float* x    = (const float*)d_in[0];  // [8,2048,512]
  const float* kern = (const float*)d_in[1];  // [2,512,1536]
  const float* bias = (const float*)d_in[2];  // [1536]
  const float* init = (const float*)d_in[3];  // [1,512]
  float* out = (float*)d_out;                 // [8,2048,512]

  char* ws = (char*)d_ws;
  unsigned short* xb = (unsigned short*)ws;                      // 16.8 MB
  size_t off = (size_t)Bn * (Tn + 1) * Cn * 2;
  unsigned short* kT = (unsigned short*)(ws + off);              // 3.1 MB
  off += (size_t)Nn * Kn * 2;
  unsigned short* gates = (unsigned short*)(ws + off);           // 50.3 MB (bf16)
  off += (size_t)Mn * Nn * 2;
  float* aggA = (float*)(ws + off);  off += (size_t)Bn * NC * Un * 4;   // 2 MB
  float* aggB = (float*)(ws + off);  off += (size_t)Bn * NC * Un * 4;   // 2 MB
  float* prefH = (float*)(ws + off); off += (size_t)Bn * NC * Un * 4;   // 2 MB
  int* flags = (int*)(ws + off);                                        // 4 KB

  prep<<<CONVX_BLOCKS + CONVK_BLOCKS + FLAG_BLOCKS, 256, 0, stream>>>(x, xb, kern, kT, flags);
  gemm_gates<<<dim3(Mn / 128, Nn / 128), 256, 0, stream>>>(xb, kT, bias, gates);
  scan_one<<<Bn * NC, 256, 0, stream>>>(gates, aggA, aggB, prefH, init, out, flags);
}

// Round 16
// 183.280 us; speedup vs baseline: 7.9417x; 7.9417x over previous
//
#include <hip/hip_runtime.h>

// QRNN: B=8 T=2048 C=512 U=512 W=2
// R11b — same as R11 but fixes the compile error (f32x4 'zero' assigned to
// float4 av0/av1; now uses make_float4). Eliminate conv_x: GEMM A-operand
// reg-staged DIRECTLY from x (f32), same f2bf rounding (bit-identical gates),
// same LDS swizzle; B unchanged via global_load_lds. Scans = R5-exact trio.
// Graph: conv_k -> gemm -> A -> B -> C (5 dispatches, xb buffer gone).

#define Bn 8
#define Tn 2048
#define Cn 512
#define Un 512
#define Nn 1536
#define Kn 1024
#define Mn (Bn * Tn)
#define NC 32   // chunks per sequence (R5-exact)
#define CL 64   // chunk length (NC*CL == Tn)

using bf16x8 = __attribute__((ext_vector_type(8))) __bf16;
using f32x4  = __attribute__((ext_vector_type(4))) float;
using ushort8v = __attribute__((ext_vector_type(8))) unsigned short;

__device__ __forceinline__ void async16(const void* g, void* l) {
  __builtin_amdgcn_global_load_lds((const __attribute__((address_space(1))) void*)g,
                                   (__attribute__((address_space(3))) void*)l, 16, 0, 0);
}

__device__ __forceinline__ unsigned short f2bf(float v) {
  union { float f; unsigned u; } c; c.f = v;
  unsigned u = c.u;
  return (unsigned short)((u + 0x7fffu + ((u >> 16) & 1u)) >> 16);  // RNE
}

__device__ __forceinline__ float bf2f(unsigned short h) {
  union { unsigned u; float f; } c; c.u = ((unsigned)h) << 16;
  return c.f;
}

__device__ __forceinline__ float fast_sigmoid(float x) {
  float e = __builtin_amdgcn_exp2f(-1.4426950408889634f * x);
  return __builtin_amdgcn_rcpf(1.0f + e);
}
__device__ __forceinline__ float fast_tanh(float x) {
  float e = __builtin_amdgcn_exp2f(-2.8853900817779268f * x);
  return 2.0f * __builtin_amdgcn_rcpf(1.0f + e) - 1.0f;
}

// ---- 1. kernel -> bf16 transposed [N][K] (unchanged) ------------------------
__global__ __launch_bounds__(256) void conv_k(const float* __restrict__ kern,
                                              unsigned short* __restrict__ kT) {
  __shared__ float tile[32][33];
  int kb = blockIdx.x, nb = blockIdx.y;       // grid (32, 48)
  int tx = threadIdx.x & 31, ty = threadIdx.x >> 5;
#pragma unroll
  for (int i = 0; i < 4; i++)
    tile[ty + i * 8][tx] = kern[(size_t)(kb * 32 + ty + i * 8) * Nn + nb * 32 + tx];
  __syncthreads();
#pragma unroll
  for (int i = 0; i < 4; i++) {
    int n = nb * 32 + ty + i * 8;
    int k = kb * 32 + tx;
    kT[(size_t)n * Kn + k] = f2bf(tile[tx][ty + i * 8]);
  }
}

// ---- 2. MFMA GEMM; A staged from x directly (f32 -> bf16 in regs) -----------
// A-operand im2col: row m=(b,t), K-cols [x[t-1,:], x[t,:]].  For K-col c:
//   c < 512 -> x[t-1][c] (zeros when t==0);  c >= 512 -> x[t][c-512].
// The k0>=512 crossing is wave-uniform; skq permutation keeps each 8-lane
// group's loads in one contiguous 256B span (coalesced).
__global__ __launch_bounds__(256) void gemm_gates(const float* __restrict__ x,
                                                  const unsigned short* __restrict__ kT,
                                                  const float* __restrict__ bias,
                                                  unsigned short* __restrict__ gates) {
  __shared__ unsigned short As[128 * 64];   // 16 KB
  __shared__ unsigned short Bs[128 * 64];   // 16 KB
  const int tid = threadIdx.x;
  const int m0 = blockIdx.x * 128;
  const int n0 = blockIdx.y * 128;
  const int batch = m0 / Tn;                // tiles never cross batch
  const int t0 = m0 - batch * Tn;           // first t of tile within batch
  const int lane = tid & 63;
  const int w = tid >> 6, wr = w >> 1, wc = w & 1;

  // Staging geometry (identical LDS layout to the proven R5 kernel):
  // call j covers LDS 16B-slots [j*256 + tid]; slot holds frag kq'=skq of row srow+j*32.
  const int srow = (w << 3) + (lane >> 3);
  const int skq  = (lane & 7) ^ (lane >> 3);
  const unsigned short* bStage = kT + (size_t)(n0 + srow) * Kn + (skq << 3);

  f32x4 zero = {0.f, 0.f, 0.f, 0.f};
  f32x4 acc[4][4];
#pragma unroll
  for (int i = 0; i < 4; i++)
#pragma unroll
    for (int j = 0; j < 4; j++) acc[i][j] = zero;

  const int rA0 = wr * 64 + (lane & 15);    // frag row base for A reads
  const int rB0 = wc * 64 + (lane & 15);
  const int swz = lane & 7;                 // row&7 for frag reads

  const float4 f4zero = make_float4(0.f, 0.f, 0.f, 0.f);

  for (int k0 = 0; k0 < Kn; k0 += 64) {
    const int cross = (k0 >= 512) ? 1 : 0;          // wave-uniform
    const int cc = (k0 & 511) + (skq << 3);         // column within x row
    float4 av0[4], av1[4];
#pragma unroll
    for (int j = 0; j < 4; j++) {
      // B: async global->LDS (unchanged)
      async16(bStage + (size_t)(j << 5) * Kn + k0, &Bs[(j * 256 + tid) * 8]);
      // A: direct f32 loads from x
      int rowt = t0 + srow + j * 32 + cross;        // padded-row index (0 => t-1 < 0)
      if (rowt != 0) {
        const float* xp = x + (size_t)(batch * Tn + rowt - 1) * Cn + cc;
        av0[j] = *(const float4*)xp;
        av1[j] = *(const float4*)(xp + 4);
      } else {
        av0[j] = f4zero; av1[j] = f4zero;
      }
    }
#pragma unroll
    for (int j = 0; j < 4; j++) {
      ushort8v us;
      us[0] = f2bf(av0[j].x); us[1] = f2bf(av0[j].y);
      us[2] = f2bf(av0[j].z); us[3] = f2bf(av0[j].w);
      us[4] = f2bf(av1[j].x); us[5] = f2bf(av1[j].y);
      us[6] = f2bf(av1[j].z); us[7] = f2bf(av1[j].w);
      *(ushort8v*)&As[(j * 256 + tid) * 8] = us;    // same swizzled slot as before
    }
    __builtin_amdgcn_s_waitcnt(0);
    __syncthreads();

#pragma unroll
    for (int ks = 0; ks < 2; ks++) {
      const int col = (((ks << 2) + (lane >> 4)) ^ swz) << 3;  // swizzled 16B col
      bf16x8 af[4], bf[4];
#pragma unroll
      for (int i = 0; i < 4; i++) {
        af[i] = *(const bf16x8*)&As[(rA0 + i * 16) * 64 + col];
        bf[i] = *(const bf16x8*)&Bs[(rB0 + i * 16) * 64 + col];
      }
#pragma unroll
      for (int i = 0; i < 4; i++)
#pragma unroll
        for (int j = 0; j < 4; j++)
          acc[i][j] = __builtin_amdgcn_mfma_f32_16x16x32_bf16(af[i], bf[j], acc[i][j], 0, 0, 0);
    }
    __syncthreads();
  }

  const int region = blockIdx.y >> 2;       // 0=z(tanh) 1=f(sig) 2=o(sig)
  const int rowB = wr * 64 + (lane >> 4) * 4;
  const int colB = wc * 64 + (lane & 15);
#pragma unroll
  for (int i = 0; i < 4; i++)
#pragma unroll
    for (int j = 0; j < 4; j++)
#pragma unroll
      for (int r = 0; r < 4; r++) {
        int mm = m0 + rowB + i * 16 + r;
        int nn = n0 + colB + j * 16;
        float g = acc[i][j][r] + bias[nn];
        float a = (region == 0) ? fast_tanh(g) : fast_sigmoid(g);
        gates[(size_t)mm * Nn + nn] = f2bf(a);
      }
}

// ---- 3. per-chunk affine (R5-exact): grid 512 = (chunk, half-of-u) ----------
__global__ __launch_bounds__(256) void scan_phaseA(const unsigned short* __restrict__ gates,
                                                   float* __restrict__ aArr,
                                                   float* __restrict__ bArr) {
  int chunk = blockIdx.x >> 1;
  int u = (blockIdx.x & 1) * 256 + threadIdx.x;
  int b = chunk >> 5, c = chunk & (NC - 1);
  const unsigned short* gp = gates + (size_t)(b * Tn + c * CL) * Nn;
  float a = 1.0f, bv = 0.0f;
#pragma unroll 4
  for (int t = 0; t < CL; t++) {
    float z = bf2f(gp[u]);
    float f = bf2f(gp[Un + u]);
    a *= f;
    bv = f * bv + (1.0f - f) * z;
    gp += Nn;
  }
  aArr[(size_t)chunk * Un + u] = a;
  bArr[(size_t)chunk * Un + u] = bv;
}

// ---- 4. scan over chunks (R5-exact) -----------------------------------------
__global__ __launch_bounds__(256) void scan_phaseB(const float* __restrict__ aArr,
                                                   const float* __restrict__ bArr,
                                                   const float* __restrict__ init,
                                                   float* __restrict__ hstart) {
  int idx = blockIdx.x * 256 + threadIdx.x; // 0..4095 = (b,u)
  int b = idx >> 9, u = idx & (Un - 1);
  float h = init[u];
  for (int c = 0; c < NC; c++) {
    size_t offc = (size_t)(b * NC + c) * Un + u;
    hstart[offc] = h;
    h = aArr[offc] * h + bArr[offc];
  }
}

// ---- 5. replay chunk with known h_start, apply output gate (R5-exact) -------
__global__ __launch_bounds__(256) void scan_phaseC(const unsigned short* __restrict__ gates,
                                                   const float* __restrict__ hstart,
                                                   float* __restrict__ out) {
  int chunk = blockIdx.x >> 1;
  int u = (blockIdx.x & 1) * 256 + threadIdx.x;
  int b = chunk >> 5, c = chunk & (NC - 1);
  const unsigned short* gp = gates + (size_t)(b * Tn + c * CL) * Nn;
  float* op = out + (size_t)(b * Tn + c * CL) * Un;
  float h = hstart[(size_t)chunk * Un + u];
#pragma unroll 4
  for (int t = 0; t < CL; t++) {
    float z = bf2f(gp[u]);
    float f = bf2f(gp[Un + u]);
    float o = bf2f(gp[2 * Un + u]);
    h = f * h + (1.0f - f) * z;
    op[u] = h * o;
    gp += Nn;
    op += Un;
  }
}

extern "C" void kernel_launch(void* const* d_in, const int* in_sizes, int n_in,
                              void* d_out, int out_size, void* d_ws, size_t ws_size,
                              hipStream_t stream) {
  const float* x    = (const float*)d_in[0];  // [8,2048,512]
  const float* kern = (const float*)d_in[1];  // [2,512,1536]
  const float* bias = (const float*)d_in[2];  // [1536]
  const float* init = (const float*)d_in[3];  // [1,512]
  float* out = (float*)d_out;                 // [8,2048,512]

  char* ws = (char*)d_ws;
  unsigned short* kT = (unsigned short*)ws;                      // 3.1 MB
  size_t off = (size_t)Nn * Kn * 2;
  unsigned short* gates = (unsigned short*)(ws + off);           // 50.3 MB (bf16)
  off += (size_t)Mn * Nn * 2;
  float* aArr = (float*)(ws + off);  off += (size_t)Bn * NC * Un * 4;   // 0.5 MB
  float* bArr = (float*)(ws + off);  off += (size_t)Bn * NC * Un * 4;   // 0.5 MB
  float* hstart = (float*)(ws + off);                                   // 0.5 MB

  conv_k<<<dim3(32, 48), 256, 0, stream>>>(kern, kT);
  gemm_gates<<<dim3(Mn / 128, Nn / 128), 256, 0, stream>>>(x, kT, bias, gates);
  scan_phaseA<<<Bn * NC * 2, 256, 0, stream>>>(gates, aArr, bArr);
  scan_phaseB<<<(Bn * Un) / 256, 256, 0, stream>>>(aArr, bArr, init, hstart);
  scan_phaseC<<<Bn * NC * 2, 256, 0, stream>>>(gates, hstart, out);
}